// Round 1
// baseline (201.553 us; speedup 1.0000x reference)
//
#include <hip/hip_runtime.h>
#include <hip/hip_bf16.h>
#include <stdint.h>

typedef __bf16 bf16x8 __attribute__((ext_vector_type(8)));
typedef float f32x4 __attribute__((ext_vector_type(4)));

#define EPS 1e-8f

// ---------------------------------------------------------------------------
// Single fused kernel: 512 threads = 8 waves, 128 x-rows/block, all 64 protos.
//
// Proto norms are now computed IN the staging loop (no separate kernel, no
// d_ws usage): for staging iteration j, wave w loads exactly proto row
// r = w + 8j with lane == chunk index, so the row's square-sum is a free
// 64-lane shfl_xor reduction over the fp32 values already in registers.
// Result goes to pn_lds[64] (separate 256 B LDS array, read in the epilogue).
//
// Protos converted fp32->bf16 into LDS (XOR-swizzled 16B chunks, 64 KiB).
// x loaded fp32 straight into registers in MFMA A-fragment layout, converted
// to bf16 in-flight; fp32 row norms from the same loads.
// C/D binding: the m89/m91-verified mapping — D row (x-row) = quad*4+reg,
// D col (proto idx) = lane&15. Output is fp32 (reference output dtype).
// No __syncthreads inside the K loop (LDS is read-only there).
// ---------------------------------------------------------------------------
__global__ __launch_bounds__(512, 4) void protonet_main_kernel(
    const float* __restrict__ x,
    const float* __restrict__ proto,
    float* __restrict__ out) {
  __shared__ char lds[64 * 1024];  // protos (bf16) during K loop, out-staging after
  __shared__ float pn_lds[64];     // proto norms, written during staging

  const int tid = threadIdx.x;
  const int wave = tid >> 6;
  const int lane = tid & 63;

  // ---- stage prototypes global(fp32) -> LDS(bf16), XOR swizzle by row ----
  // chunk i = tid + j*512 (8 elems each): row = i>>6 = wave + 8j,
  // cc = i&63 = lane, stored at row*1024 + (cc ^ (row&15))*16.
  // Per (wave, j) one full proto row -> fold in the row-norm reduction.
#pragma unroll
  for (int j = 0; j < 8; ++j) {
    const int row = wave + 8 * j;
    const int cc = lane;
    const int sc = cc ^ (row & 15);
    const float* src = proto + (size_t)row * 512 + cc * 8;
    const f32x4 p0 = *(const f32x4*)(src);
    const f32x4 p1 = *(const f32x4*)(src + 4);
    bf16x8 b;
    float s = 0.f;
#pragma unroll
    for (int e = 0; e < 4; ++e) {
      s += p0[e] * p0[e] + p1[e] * p1[e];
      b[e] = (__bf16)p0[e];
      b[e + 4] = (__bf16)p1[e];
    }
    *(bf16x8*)(lds + row * 1024 + sc * 16) = b;
    // 64-lane reduction of the row's square-sum (fp32, matches old kernel)
#pragma unroll
    for (int off = 1; off < 64; off <<= 1) s += __shfl_xor(s, off);
    if (lane == 0) pn_lds[row] = sqrtf(s);
  }
  __syncthreads();

  const int m = lane & 15;     // x-row within 16-row tile (A-dim) / proto col (B-dim)
  const int quad = lane >> 4;  // k-subchunk selector

  const long rowbase = (long)blockIdx.x * 128 + wave * 16;
  const float* xptr = x + (size_t)(rowbase + m) * 512 + quad * 8;

  f32x4 acc0 = {0.f, 0.f, 0.f, 0.f};
  f32x4 acc1 = {0.f, 0.f, 0.f, 0.f};
  f32x4 acc2 = {0.f, 0.f, 0.f, 0.f};
  f32x4 acc3 = {0.f, 0.f, 0.f, 0.f};
  float xnsq = 0.f;

#pragma unroll 4
  for (int kc = 0; kc < 16; ++kc) {
    // A fragment source: x[rowbase+m][kc*32 + quad*8 + 0..7], fp32
    const f32x4 v0 = *(const f32x4*)(xptr + kc * 32);
    const f32x4 v1 = *(const f32x4*)(xptr + kc * 32 + 4);
    bf16x8 a;
#pragma unroll
    for (int e = 0; e < 4; ++e) {
      xnsq += v0[e] * v0[e];
      xnsq += v1[e] * v1[e];
      a[e] = (__bf16)v0[e];
      a[e + 4] = (__bf16)v1[e];
    }
    // B fragments: proto[16t+m][kc*32 + quad*8 + 0..7], swizzled chunk addr
    const int ccq = kc * 4 + quad;
    bf16x8 b0 = *(const bf16x8*)(lds + (0 * 16 + m) * 1024 + (ccq ^ m) * 16);
    bf16x8 b1 = *(const bf16x8*)(lds + (1 * 16 + m) * 1024 + (ccq ^ m) * 16);
    bf16x8 b2 = *(const bf16x8*)(lds + (2 * 16 + m) * 1024 + (ccq ^ m) * 16);
    bf16x8 b3 = *(const bf16x8*)(lds + (3 * 16 + m) * 1024 + (ccq ^ m) * 16);
    acc0 = __builtin_amdgcn_mfma_f32_16x16x32_bf16(a, b0, acc0, 0, 0, 0);
    acc1 = __builtin_amdgcn_mfma_f32_16x16x32_bf16(a, b1, acc1, 0, 0, 0);
    acc2 = __builtin_amdgcn_mfma_f32_16x16x32_bf16(a, b2, acc2, 0, 0, 0);
    acc3 = __builtin_amdgcn_mfma_f32_16x16x32_bf16(a, b3, acc3, 0, 0, 0);
  }

  // ---- row norm of row m: sum partials across lanes {m,m+16,m+32,m+48} ----
  xnsq += __shfl_xor(xnsq, 16);
  xnsq += __shfl_xor(xnsq, 32);
  const float xn = sqrtf(xnsq);  // lane holds xn of x-row (lane&15)

  // xn for the 4 D-rows this lane owns: D row = quad*4 + r
  float xnr[4];
#pragma unroll
  for (int r = 0; r < 4; ++r) xnr[r] = __shfl(xn, quad * 4 + r);

  // pn for the 4 proto tiles this lane owns: proto idx = 16t + m
  // (pn_lds written before the first barrier, never overwritten)
  float pnv[4];
#pragma unroll
  for (int t = 0; t < 4; ++t) pnv[t] = pn_lds[16 * t + m];

  // ---- all waves done reading protos; reuse LDS as fp32 [128][64] ----
  __syncthreads();
  float* outs = (float*)lds;
  const f32x4 accs[4] = {acc0, acc1, acc2, acc3};
#pragma unroll
  for (int t = 0; t < 4; ++t) {
#pragma unroll
    for (int r = 0; r < 4; ++r) {
      float denom = fmaxf(xnr[r] * pnv[t], EPS);
      // D[quad*4+r][16t+m] = dot(x[rowbase+quad*4+r], proto[16t+m])
      outs[(wave * 16 + quad * 4 + r) * 64 + 16 * t + m] = -accs[t][r] / denom;
    }
  }
  __syncthreads();

  // ---- coalesced copy-out: block's output span is contiguous 32 KiB ----
  uint4* dst = (uint4*)(out + (size_t)blockIdx.x * 128 * 64);
  const uint4* src = (const uint4*)lds;
#pragma unroll
  for (int k = 0; k < 4; ++k) dst[tid + 512 * k] = src[tid + 512 * k];
}

// ---------------------------------------------------------------------------
extern "C" void kernel_launch(void* const* d_in, const int* in_sizes, int n_in,
                              void* d_out, int out_size, void* d_ws, size_t ws_size,
                              hipStream_t stream) {
  const float* x = (const float*)d_in[0];      // fp32 [B,512]
  const float* proto = (const float*)d_in[1];  // fp32 [64,512]
  float* out = (float*)d_out;                  // fp32 [B,64]
  (void)d_ws; (void)ws_size;                   // workspace no longer used

  const int B = in_sizes[0] / 512;  // 65536

  protonet_main_kernel<<<dim3(B / 128), dim3(512), 0, stream>>>(x, proto, out);
}

// Round 2
// 193.206 us; speedup vs baseline: 1.0432x; 1.0432x over previous
//
#include <hip/hip_runtime.h>
#include <hip/hip_bf16.h>
#include <stdint.h>

typedef __bf16 bf16x8 __attribute__((ext_vector_type(8)));
typedef float f32x4 __attribute__((ext_vector_type(4)));

#define EPS 1e-8f

// ---------------------------------------------------------------------------
// Single fused kernel: 512 threads = 8 waves, 128 x-rows/block, all 64 protos.
//
// Proto norms computed in the staging loop (wave w stages row w+8j, lane ==
// chunk idx -> free 64-lane shfl_xor reduction), stored to pn_lds[64].
//
// Protos fp32->bf16 in LDS (XOR-swizzled 16B chunks, 64 KiB). x loaded fp32
// nontemporally into registers in MFMA A-fragment layout, converted to bf16
// in-flight; fp32 row norms from the same loads.
//
// This round vs last:
//  - first x-group prefetched BEFORE the staging barrier (overlap prologue)
//  - explicit 1-ahead software pipeline in the K loop
//  - epilogue: direct nontemporal dword stores (no LDS round-trip, no
//    barriers; 64B segments write-combine in L2)
//
// C/D binding: m89/m91-verified — D row (x-row) = quad*4+reg, D col (proto
// idx) = lane&15. Output fp32.
// ---------------------------------------------------------------------------
__global__ __launch_bounds__(512, 4) void protonet_main_kernel(
    const float* __restrict__ x,
    const float* __restrict__ proto,
    float* __restrict__ out) {
  __shared__ char lds[64 * 1024];  // protos (bf16) during K loop
  __shared__ float pn_lds[64];     // proto norms, written during staging

  const int tid = threadIdx.x;
  const int wave = tid >> 6;
  const int lane = tid & 63;
  const int m = lane & 15;     // x-row within 16-row tile / proto col
  const int quad = lane >> 4;  // k-subchunk selector

  const long rowbase = (long)blockIdx.x * 128 + wave * 16;
  const float* xptr = x + (size_t)(rowbase + m) * 512 + quad * 8;

  // ---- prefetch first x group before the barrier (hides staging latency) --
  f32x4 v0 = __builtin_nontemporal_load((const f32x4*)(xptr));
  f32x4 v1 = __builtin_nontemporal_load((const f32x4*)(xptr + 4));

  // ---- stage prototypes global(fp32) -> LDS(bf16), XOR swizzle by row ----
  // chunk i = tid + j*512 (8 elems each): row = i>>6 = wave + 8j,
  // cc = i&63 = lane, stored at row*1024 + (cc ^ (row&15))*16.
  // Per (wave, j) one full proto row -> fold in the row-norm reduction.
#pragma unroll
  for (int j = 0; j < 8; ++j) {
    const int row = wave + 8 * j;
    const int cc = lane;
    const int sc = cc ^ (row & 15);
    const float* src = proto + (size_t)row * 512 + cc * 8;
    const f32x4 p0 = *(const f32x4*)(src);
    const f32x4 p1 = *(const f32x4*)(src + 4);
    bf16x8 b;
    float s = 0.f;
#pragma unroll
    for (int e = 0; e < 4; ++e) {
      s += p0[e] * p0[e] + p1[e] * p1[e];
      b[e] = (__bf16)p0[e];
      b[e + 4] = (__bf16)p1[e];
    }
    *(bf16x8*)(lds + row * 1024 + sc * 16) = b;
#pragma unroll
    for (int off = 1; off < 64; off <<= 1) s += __shfl_xor(s, off);
    if (lane == 0) pn_lds[row] = sqrtf(s);
  }
  __syncthreads();

  f32x4 acc0 = {0.f, 0.f, 0.f, 0.f};
  f32x4 acc1 = {0.f, 0.f, 0.f, 0.f};
  f32x4 acc2 = {0.f, 0.f, 0.f, 0.f};
  f32x4 acc3 = {0.f, 0.f, 0.f, 0.f};
  float xnsq = 0.f;

#pragma unroll 4
  for (int kc = 0; kc < 16; ++kc) {
    // 1-ahead prefetch of the next A-fragment source (nontemporal: x is
    // streamed exactly once, keep it out of L2's way)
    f32x4 n0, n1;
    if (kc < 15) {
      n0 = __builtin_nontemporal_load((const f32x4*)(xptr + (kc + 1) * 32));
      n1 = __builtin_nontemporal_load((const f32x4*)(xptr + (kc + 1) * 32 + 4));
    }
    bf16x8 a;
#pragma unroll
    for (int e = 0; e < 4; ++e) {
      xnsq += v0[e] * v0[e];
      xnsq += v1[e] * v1[e];
      a[e] = (__bf16)v0[e];
      a[e + 4] = (__bf16)v1[e];
    }
    // B fragments: proto[16t+m][kc*32 + quad*8 + 0..7], swizzled chunk addr
    const int ccq = kc * 4 + quad;
    bf16x8 b0 = *(const bf16x8*)(lds + (0 * 16 + m) * 1024 + (ccq ^ m) * 16);
    bf16x8 b1 = *(const bf16x8*)(lds + (1 * 16 + m) * 1024 + (ccq ^ m) * 16);
    bf16x8 b2 = *(const bf16x8*)(lds + (2 * 16 + m) * 1024 + (ccq ^ m) * 16);
    bf16x8 b3 = *(const bf16x8*)(lds + (3 * 16 + m) * 1024 + (ccq ^ m) * 16);
    acc0 = __builtin_amdgcn_mfma_f32_16x16x32_bf16(a, b0, acc0, 0, 0, 0);
    acc1 = __builtin_amdgcn_mfma_f32_16x16x32_bf16(a, b1, acc1, 0, 0, 0);
    acc2 = __builtin_amdgcn_mfma_f32_16x16x32_bf16(a, b2, acc2, 0, 0, 0);
    acc3 = __builtin_amdgcn_mfma_f32_16x16x32_bf16(a, b3, acc3, 0, 0, 0);
    v0 = n0;
    v1 = n1;
  }

  // ---- row norm of row m: sum partials across lanes {m,m+16,m+32,m+48} ----
  xnsq += __shfl_xor(xnsq, 16);
  xnsq += __shfl_xor(xnsq, 32);
  const float xn = sqrtf(xnsq);  // lane holds xn of x-row (lane&15)

  // xn for the 4 D-rows this lane owns: D row = quad*4 + r
  float xnr[4];
#pragma unroll
  for (int r = 0; r < 4; ++r) xnr[r] = __shfl(xn, quad * 4 + r);

  // pn for the 4 proto tiles this lane owns: proto idx = 16t + m
  float pnv[4];
#pragma unroll
  for (int t = 0; t < 4; ++t) pnv[t] = pn_lds[16 * t + m];

  // ---- epilogue: direct nontemporal stores, no barriers ----
  // D[wave*16 + quad*4 + r][16t+m]; per instruction 64 lanes hit 4 rows x
  // 64B contiguous col-segments; L2 write-combines to full lines.
  float* orow = out + (size_t)(rowbase + quad * 4) * 64;
  const f32x4 accs[4] = {acc0, acc1, acc2, acc3};
#pragma unroll
  for (int t = 0; t < 4; ++t) {
#pragma unroll
    for (int r = 0; r < 4; ++r) {
      float denom = fmaxf(xnr[r] * pnv[t], EPS);
      __builtin_nontemporal_store(-accs[t][r] / denom,
                                  orow + (size_t)r * 64 + 16 * t + m);
    }
  }
}

// ---------------------------------------------------------------------------
extern "C" void kernel_launch(void* const* d_in, const int* in_sizes, int n_in,
                              void* d_out, int out_size, void* d_ws, size_t ws_size,
                              hipStream_t stream) {
  const float* x = (const float*)d_in[0];      // fp32 [B,512]
  const float* proto = (const float*)d_in[1];  // fp32 [64,512]
  float* out = (float*)d_out;                  // fp32 [B,64]
  (void)d_ws; (void)ws_size;                   // workspace unused

  const int B = in_sizes[0] / 512;  // 65536

  protonet_main_kernel<<<dim3(B / 128), dim3(512), 0, stream>>>(x, proto, out);
}

// Round 3
// 192.992 us; speedup vs baseline: 1.0444x; 1.0011x over previous
//
#include <hip/hip_runtime.h>
#include <hip/hip_bf16.h>
#include <stdint.h>

typedef __bf16 bf16x8 __attribute__((ext_vector_type(8)));
typedef float f32x4 __attribute__((ext_vector_type(4)));

#define EPS 1e-8f

// ---------------------------------------------------------------------------
// Single fused kernel: 512 threads = 8 waves, 128 x-rows/block, all 64 protos.
//
// Round 2 -> 3 changes (attacking the ~5.0 vs 6.3 TB/s streaming gap):
//  - 2-deep x prefetch (4 loads / 64B per lane in flight; Little's-law fix)
//  - both initial groups issued BEFORE proto staging (prologue overlap)
//  - xnsq split into 4 independent accumulators (breaks 512-cycle fmac chain)
//
// Proto norms computed in the staging loop (wave w stages row w+8j, lane ==
// chunk idx -> free 64-lane shfl_xor reduction), stored to pn_lds[64].
// Protos fp32->bf16 in LDS (XOR-swizzled 16B chunks, 64 KiB).
// C/D binding: m89/m91-verified — D row (x-row) = quad*4+reg, D col (proto
// idx) = lane&15. Output fp32, direct nontemporal stores, no barriers.
// ---------------------------------------------------------------------------
__global__ __launch_bounds__(512, 4) void protonet_main_kernel(
    const float* __restrict__ x,
    const float* __restrict__ proto,
    float* __restrict__ out) {
  __shared__ char lds[64 * 1024];  // protos (bf16) during K loop
  __shared__ float pn_lds[64];     // proto norms, written during staging

  const int tid = threadIdx.x;
  const int wave = tid >> 6;
  const int lane = tid & 63;
  const int m = lane & 15;     // x-row within 16-row tile / proto col
  const int quad = lane >> 4;  // k-subchunk selector

  const long rowbase = (long)blockIdx.x * 128 + wave * 16;
  const float* xptr = x + (size_t)(rowbase + m) * 512 + quad * 8;

  // ---- 2-deep prefetch of x groups kc=0,1 BEFORE staging (overlap) ----
  f32x4 c0 = __builtin_nontemporal_load((const f32x4*)(xptr));
  f32x4 c1 = __builtin_nontemporal_load((const f32x4*)(xptr + 4));
  f32x4 d0 = __builtin_nontemporal_load((const f32x4*)(xptr + 32));
  f32x4 d1 = __builtin_nontemporal_load((const f32x4*)(xptr + 36));

  // ---- stage prototypes global(fp32) -> LDS(bf16), XOR swizzle by row ----
  // chunk i = tid + j*512 (8 elems each): row = i>>6 = wave + 8j,
  // cc = i&63 = lane, stored at row*1024 + (cc ^ (row&15))*16.
  // Per (wave, j) one full proto row -> fold in the row-norm reduction.
#pragma unroll
  for (int j = 0; j < 8; ++j) {
    const int row = wave + 8 * j;
    const int cc = lane;
    const int sc = cc ^ (row & 15);
    const float* src = proto + (size_t)row * 512 + cc * 8;
    const f32x4 p0 = *(const f32x4*)(src);
    const f32x4 p1 = *(const f32x4*)(src + 4);
    bf16x8 b;
    float s = 0.f;
#pragma unroll
    for (int e = 0; e < 4; ++e) {
      s += p0[e] * p0[e] + p1[e] * p1[e];
      b[e] = (__bf16)p0[e];
      b[e + 4] = (__bf16)p1[e];
    }
    *(bf16x8*)(lds + row * 1024 + sc * 16) = b;
#pragma unroll
    for (int off = 1; off < 64; off <<= 1) s += __shfl_xor(s, off);
    if (lane == 0) pn_lds[row] = sqrtf(s);
  }
  __syncthreads();

  f32x4 acc0 = {0.f, 0.f, 0.f, 0.f};
  f32x4 acc1 = {0.f, 0.f, 0.f, 0.f};
  f32x4 acc2 = {0.f, 0.f, 0.f, 0.f};
  f32x4 acc3 = {0.f, 0.f, 0.f, 0.f};
  // 4 independent norm accumulators (break the dependent-fmac chain)
  float xs0 = 0.f, xs1 = 0.f, xs2 = 0.f, xs3 = 0.f;

#pragma unroll 4
  for (int kc = 0; kc < 16; ++kc) {
    // prefetch kc+2 (keeps 4 loads / 64 B per lane outstanding)
    f32x4 n0, n1;
    if (kc < 14) {
      n0 = __builtin_nontemporal_load((const f32x4*)(xptr + (kc + 2) * 32));
      n1 = __builtin_nontemporal_load((const f32x4*)(xptr + (kc + 2) * 32 + 4));
    }
    bf16x8 a;
    xs0 += c0[0] * c0[0] + c0[1] * c0[1];
    xs1 += c0[2] * c0[2] + c0[3] * c0[3];
    xs2 += c1[0] * c1[0] + c1[1] * c1[1];
    xs3 += c1[2] * c1[2] + c1[3] * c1[3];
#pragma unroll
    for (int e = 0; e < 4; ++e) {
      a[e] = (__bf16)c0[e];
      a[e + 4] = (__bf16)c1[e];
    }
    // B fragments: proto[16t+m][kc*32 + quad*8 + 0..7], swizzled chunk addr
    const int ccq = kc * 4 + quad;
    bf16x8 b0 = *(const bf16x8*)(lds + (0 * 16 + m) * 1024 + (ccq ^ m) * 16);
    bf16x8 b1 = *(const bf16x8*)(lds + (1 * 16 + m) * 1024 + (ccq ^ m) * 16);
    bf16x8 b2 = *(const bf16x8*)(lds + (2 * 16 + m) * 1024 + (ccq ^ m) * 16);
    bf16x8 b3 = *(const bf16x8*)(lds + (3 * 16 + m) * 1024 + (ccq ^ m) * 16);
    acc0 = __builtin_amdgcn_mfma_f32_16x16x32_bf16(a, b0, acc0, 0, 0, 0);
    acc1 = __builtin_amdgcn_mfma_f32_16x16x32_bf16(a, b1, acc1, 0, 0, 0);
    acc2 = __builtin_amdgcn_mfma_f32_16x16x32_bf16(a, b2, acc2, 0, 0, 0);
    acc3 = __builtin_amdgcn_mfma_f32_16x16x32_bf16(a, b3, acc3, 0, 0, 0);
    // rotate pipeline registers (all static — no runtime indexing)
    c0 = d0; c1 = d1; d0 = n0; d1 = n1;
  }

  // ---- row norm of row m: sum partials across lanes {m,m+16,m+32,m+48} ----
  float xnsq = (xs0 + xs1) + (xs2 + xs3);
  xnsq += __shfl_xor(xnsq, 16);
  xnsq += __shfl_xor(xnsq, 32);
  const float xn = sqrtf(xnsq);  // lane holds xn of x-row (lane&15)

  // xn for the 4 D-rows this lane owns: D row = quad*4 + r
  float xnr[4];
#pragma unroll
  for (int r = 0; r < 4; ++r) xnr[r] = __shfl(xn, quad * 4 + r);

  // pn for the 4 proto tiles this lane owns: proto idx = 16t + m
  float pnv[4];
#pragma unroll
  for (int t = 0; t < 4; ++t) pnv[t] = pn_lds[16 * t + m];

  // ---- epilogue: direct nontemporal stores, no barriers ----
  // D[wave*16 + quad*4 + r][16t+m]; per instruction 64 lanes hit 4 rows x
  // 64B contiguous col-segments; L2 write-combines to full lines.
  float* orow = out + (size_t)(rowbase + quad * 4) * 64;
  const f32x4 accs[4] = {acc0, acc1, acc2, acc3};
#pragma unroll
  for (int t = 0; t < 4; ++t) {
#pragma unroll
    for (int r = 0; r < 4; ++r) {
      float denom = fmaxf(xnr[r] * pnv[t], EPS);
      __builtin_nontemporal_store(-accs[t][r] / denom,
                                  orow + (size_t)r * 64 + 16 * t + m);
    }
  }
}

// ---------------------------------------------------------------------------
extern "C" void kernel_launch(void* const* d_in, const int* in_sizes, int n_in,
                              void* d_out, int out_size, void* d_ws, size_t ws_size,
                              hipStream_t stream) {
  const float* x = (const float*)d_in[0];      // fp32 [B,512]
  const float* proto = (const float*)d_in[1];  // fp32 [64,512]
  float* out = (float*)d_out;                  // fp32 [B,64]
  (void)d_ws; (void)ws_size;                   // workspace unused

  const int B = in_sizes[0] / 512;  // 65536

  protonet_main_kernel<<<dim3(B / 128), dim3(512), 0, stream>>>(x, proto, out);
}